// Round 5
// baseline (171.020 us; speedup 1.0000x reference)
//
#include <hip/hip_runtime.h>

typedef _Float16 f16;
typedef _Float16 f16x4 __attribute__((ext_vector_type(4)));
typedef _Float16 f16x8 __attribute__((ext_vector_type(8)));
typedef float f32x4 __attribute__((ext_vector_type(4)));
typedef unsigned int u32;

#define MFMA16(a,b,c) __builtin_amdgcn_mfma_f32_16x16x32_f16(a,b,c,0,0,0)

// raw barrier: orders LDS (lgkmcnt) but does NOT drain vmcnt (neutral vs
// __syncthreads in R3; kept so hG stores never gate a barrier).
#define BAR() asm volatile("s_waitcnt lgkmcnt(0)\n\ts_barrier" ::: "memory")

// packed weight f16-element offsets in d_ws
#define OFF_A0 0
#define OFF_B0 8192
#define OFF_AW 16384
#define OFF_BW 65536
#define OFF_AL 114688
#define OFF_BE 118784
#define OFF_O0 122880
#define OFF_O1 126976
#define OFF_O2 143360
#define PACK_TOTAL 145408
#define FLAG_ELEM 153600              // u32 flags[1024] at f16-elem 153600 (byte 307200)
#define OFF_HH 262144                 // h plane (single f16): 8192 mt * 512

struct PackSrcs { const float* p[9]; };

// One fused pack kernel: W[K][N] fp32 -> MFMA fragment order f16.
// frag element (nt,kt,lane,j) = W[kt*32 + (lane>>4)*8 + j][nt*16 + (lane&15)]
// Tail range zeroes the 1024 per-(tile,octet) sync flags each iteration.
__global__ __launch_bounds__(256) void pack_all(PackSrcs ps, f16* __restrict__ dst){
  int idx = blockIdx.x*256 + threadIdx.x;
  if (idx >= PACK_TOTAL + 1024) return;
  if (idx >= PACK_TOTAL){ ((u32*)(dst + FLAG_ELEM))[idx - PACK_TOTAL] = 0u; return; }
  const float* src; int base, Kreal, Nreal, KT;
  if (idx < 16384){
    if (idx < 8192){ src=ps.p[0]; base=0; } else { src=ps.p[1]; base=8192; }
    Kreal=38; Nreal=128; KT=2;
  } else if (idx < 65536){
    int s=(idx-16384)>>14; src=ps.p[2]+s*16384; base=16384+s*16384; Kreal=128; Nreal=128; KT=4;
  } else if (idx < 114688){
    int s=(idx-65536)>>14; src=ps.p[3]+s*16384; base=65536+s*16384; Kreal=128; Nreal=128; KT=4;
  } else if (idx < 122880){
    if (idx<118784){ src=ps.p[4]; base=114688; } else { src=ps.p[5]; base=118784; }
    Kreal=128; Nreal=32; KT=4;
  } else if (idx < 126976){
    src=ps.p[6]; base=122880; Kreal=32; Nreal=128; KT=1;
  } else if (idx < 143360){
    src=ps.p[7]; base=126976; Kreal=128; Nreal=128; KT=4;
  } else {
    src=ps.p[8]; base=143360; Kreal=128; Nreal=3; KT=4;
  }
  int local = idx - base;
  int j = local & 7, lane = (local>>3)&63, rem = local>>9;
  int kt = rem % KT, nt = rem / KT;
  int k = kt*32 + ((lane>>4)<<3) + j;
  int n = nt*16 + (lane&15);
  dst[idx] = (f16)((k<Kreal && n<Nreal) ? src[k*Nreal+n] : 0.f);
}

__device__ __forceinline__ float tanhfast(float x){
  float e = __builtin_amdgcn_exp2f(x * 2.885390082f);   // 2*log2(e)
  return 1.f - 2.f*__builtin_amdgcn_rcpf(e + 1.f);
}
__device__ __forceinline__ float expfast(float x){
  return __builtin_amdgcn_exp2f(x * 1.44269504f);
}

__device__ __forceinline__ f16x8 ldW(const f16* wp, int off, int KT, int nt, int kt, int l){
  return *(const f16x8*)(wp + off + (((nt*KT + kt)*64 + l)<<3));
}

// single-plane quadratic phase (transposed orientation, m=1 per wave)
template<int LAST>
__device__ __forceinline__ void qphase(const f16* __restrict__ Zi, f16* __restrict__ Zo,
                                       const f16x8 (&WA)[4], const f16x8 (&WB)[4],
                                       const float* __restrict__ bA,
                                       const float* __restrict__ bB,
                                       int l, int d0, int n16){
  f16x8 Bq[4];
#pragma unroll
  for (int kt=0; kt<4; ++kt) Bq[kt] = *(const f16x8*)(Zi + ((kt*64 + l)<<3));
  f32x4 a = *(const f32x4*)(bA + d0);
  f32x4 c = *(const f32x4*)(bB + d0);
#pragma unroll
  for (int kt=0; kt<4; ++kt){
    a = MFMA16(WA[kt], Bq[kt], a);
    c = MFMA16(WB[kt], Bq[kt], c);
  }
  f16x4 z4;
#pragma unroll
  for (int i=0;i<4;++i){
    float z = LAST ? tanhfast(a[i]*c[i]) : tanhfast(a[i])*tanhfast(c[i]);
    z4[i] = (f16)z;
  }
  int kt_o = d0>>5, lane_o = (((d0&31)>>3)<<4) | n16, j0 = d0&7;
  *(f16x4*)(Zo + ((kt_o*64 + lane_o)<<3) + j0) = z4;
}

// Fused persistent kernel: blocks 0-127 = recurrence (verbatim R3 structure),
// blocks 128-255 = output head on the otherwise-idle CUs, consuming hG per
// 8-timestep octet via device-scope flags (rec waves 0,1 each release-add 1;
// consumer acquire-spins for 2).
__global__ __launch_bounds__(512,2)
void lmsc_fused(const float* __restrict__ x, const float* __restrict__ init_ori,
                const f16* __restrict__ wp,
                const float* __restrict__ ba0, const float* __restrict__ bas,
                const float* __restrict__ bb0, const float* __restrict__ bbs,
                const float* __restrict__ b_al, const float* __restrict__ b_be,
                const float* __restrict__ bo0, const float* __restrict__ bo1,
                const float* __restrict__ bo2,
                f16* __restrict__ hG, u32* __restrict__ flags,
                float* __restrict__ out)
{
  // rec-role shared (≈20.5 KB)
  __shared__ __align__(16) f16 S[2][1024];
  __shared__ __align__(16) f16 Z[2][2048];
  __shared__ float biasA[4][128], biasB[4][128], biasAB[64];
  __shared__ float hbuf[512];
  __shared__ float xnL[64][8];
  // out-role shared (32 KB)
  __shared__ __align__(16) f16 o1b[16384];
  __shared__ __align__(16) f16 o2b[16384];

  const int tid = (int)threadIdx.x;
  const int l = tid & 63, wid = tid >> 6;
  const int n16 = l & 15, rhi = l >> 4;

  if (blockIdx.x < 128){
    // ================= recurrence role =================
    const int d0 = (wid<<4) + (rhi<<2);
    const int tile = (int)blockIdx.x, b = tile >> 4, Rbase = tile << 4;

    f16x8 w0A[2], w0B[2];
#pragma unroll
    for (int kt=0;kt<2;++kt){
      w0A[kt] = ldW(wp, OFF_A0, 2, wid, kt, l);
      w0B[kt] = ldW(wp, OFF_B0, 2, wid, kt, l);
    }
    f16x8 wqA[3][4], wqB[3][4];
#pragma unroll
    for (int ly=0;ly<3;++ly)
#pragma unroll
      for (int kt=0;kt<4;++kt){
        wqA[ly][kt] = ldW(wp, OFF_AW + ly*16384, 4, wid, kt, l);
        wqB[ly][kt] = ldW(wp, OFF_BW + ly*16384, 4, wid, kt, l);
      }
    f16x8 wal[4], wbe[4];
    if (wid < 2){
#pragma unroll
      for (int kt=0;kt<4;++kt){
        wal[kt] = ldW(wp, OFF_AL, 4, wid, kt, l);
        wbe[kt] = ldW(wp, OFF_BE, 4, wid, kt, l);
      }
    }

    ((u32*)S)[tid] = 0u; ((u32*)S)[tid+512] = 0u;
    if (tid < 128){
      biasA[0][tid] = ba0[tid]; biasB[0][tid] = bb0[tid];
#pragma unroll
      for (int j=0;j<3;++j){ biasA[1+j][tid] = bas[j*128+tid]; biasB[1+j][tid] = bbs[j*128+tid]; }
    }
    if (tid < 32){ biasAB[tid] = b_al[tid]; biasAB[32+tid] = b_be[tid]; }
    if (tid < 64){
      const float* xp = x + (b*64 + tid)*6;
      float s2 = 0.f;
#pragma unroll
      for (int i=0;i<6;++i) s2 += xp[i]*xp[i];
      float sn = sqrtf(s2);
      float inv = 1.f/(sn + 1e-15f);
#pragma unroll
      for (int i=0;i<6;++i) xnL[tid][i] = xp[i]*inv;
      xnL[tid][6] = sn;
    }
    __syncthreads();
    if (tid < 256){
      int r = tid & 15, cc = tid >> 4;
#pragma unroll
      for (int e=0;e<2;++e){
        int c = cc + e*16;
        float h0 = (c < 3) ? init_ori[(Rbase + r)*3 + c] : 0.f;
        hbuf[c*16 + r] = h0;
        f16 hh = (f16)h0, hl = (f16)(h0 - (float)hh);
        int k = 6 + c;
        int idx = (((k>>5)*64 + (((k&31)>>3)<<4) + r)<<3) + (k&7);
        S[0][idx] = hh; S[1][idx] = hl;
      }
    }
    if (tid < 96){
      int r2 = tid/6, c2 = tid - r2*6;
      float xv = xnL[0][c2];
      f16 xh = (f16)xv, xl = (f16)(xv - (float)xh);
      S[0][(r2<<3)+c2] = xh; S[1][(r2<<3)+c2] = xl;
    }
    __syncthreads();

    for (int t=0; t<64; ++t){
      // ---- L0 ----
      {
        f16x8 Bh[2], Bl[2];
#pragma unroll
        for (int kt=0;kt<2;++kt){
          Bh[kt] = *(const f16x8*)(&S[0][(kt*64+l)<<3]);
          Bl[kt] = *(const f16x8*)(&S[1][(kt*64+l)<<3]);
        }
        f32x4 aH = *(const f32x4*)(&biasA[0][d0]);
        f32x4 cH = *(const f32x4*)(&biasB[0][d0]);
        f32x4 aL = {0,0,0,0}, cL = {0,0,0,0};
#pragma unroll
        for (int kt=0;kt<2;++kt){
          aH = MFMA16(w0A[kt], Bh[kt], aH); aL = MFMA16(w0A[kt], Bl[kt], aL);
          cH = MFMA16(w0B[kt], Bh[kt], cH); cL = MFMA16(w0B[kt], Bl[kt], cL);
        }
        f16x4 z4;
#pragma unroll
        for (int i=0;i<4;++i)
          z4[i] = (f16)(tanhfast(aH[i]+aL[i]) * tanhfast(cH[i]+cL[i]));
        int kt_o = d0>>5, lane_o = (((d0&31)>>3)<<4) | n16, j0 = d0&7;
        *(f16x4*)(&Z[0][((kt_o*64 + lane_o)<<3) + j0]) = z4;
      }
      BAR();
      qphase<0>(Z[0], Z[1], wqA[0], wqB[0], biasA[1], biasB[1], l, d0, n16);
      BAR();
      qphase<0>(Z[1], Z[0], wqA[1], wqB[1], biasA[2], biasB[2], l, d0, n16);
      BAR();
      qphase<1>(Z[0], Z[1], wqA[2], wqB[2], biasA[3], biasB[3], l, d0, n16);
      BAR();
      // ---- P4: alpha+beta+h-update on waves 0-1; xn staging on waves 6-7 ----
      if (wid < 2){
        f16x8 q[4];
#pragma unroll
        for (int kt=0;kt<4;++kt) q[kt] = *(const f16x8*)(&Z[1][(kt*64+l)<<3]);
        f32x4 ua = *(const f32x4*)(&biasAB[d0]);
        f32x4 ub = *(const f32x4*)(&biasAB[32+d0]);
#pragma unroll
        for (int kt=0;kt<4;++kt){
          ua = MFMA16(wal[kt], q[kt], ua);
          ub = MFMA16(wbe[kt], q[kt], ub);
        }
        float sn = xnL[t][6];
        int mt = tile*64 + t;
        f16x4 hh4;
#pragma unroll
        for (int i=0;i<4;++i){
          float alv = expfast(fminf(ua[i], 80.f));
          float bev = tanhfast(ub[i]);
          int c = d0 + i;
          float hold = hbuf[c*16 + n16];
          float hn = __builtin_amdgcn_exp2f(-1.44269504f*alv*sn)*(hold - bev) + bev;
          hbuf[c*16 + n16] = hn;
          f16 hh = (f16)hn; hh4[i] = hh;
          if (t < 63){
            f16 hl = (f16)(hn - (float)hh);
            int k = 6 + c;
            int idx = (((k>>5)*64 + (((k&31)>>3)<<4) + n16)<<3) + (k&7);
            S[0][idx] = hh; S[1][idx] = hl;
          }
        }
        int lane_o = ((d0>>3)<<4) | n16;
        *(f16x4*)(hG + mt*512 + lane_o*8 + (d0&7)) = hh4;
        // publish octet: release orders this wave's hG stores; consumer waits for 2.
        if ((t & 7) == 7 && l == 0)
          __hip_atomic_fetch_add(&flags[(tile<<3) + (t>>3)], 1u,
                                 __ATOMIC_RELEASE, __HIP_MEMORY_SCOPE_AGENT);
      }
      if (t < 63 && tid >= 384 && tid < 480){
        int i2 = tid - 384;
        int r2 = i2/6, c2 = i2 - r2*6;
        float xv = xnL[t+1][c2];
        f16 xh = (f16)xv, xl = (f16)(xv - (float)xh);
        S[0][(r2<<3)+c2] = xh; S[1][(r2<<3)+c2] = xl;
      }
      BAR();
    }
  } else {
    // ================= output-head role =================
    const int r = (int)blockIdx.x - 128;       // tile index
    f16x8 W0a = ldW(wp, OFF_O0, 1, wid, 0, l);
    f16x8 W1a[4], W2a[4];
#pragma unroll
    for (int kt=0;kt<4;++kt){ W1a[kt]=ldW(wp,OFF_O1,4,wid,kt,l); W2a[kt]=ldW(wp,OFF_O2,4,0,kt,l); }
    const int d0 = wid*16 + rhi*4;
    const f32x4 b0v = *(const f32x4*)(bo0 + d0);
    const f32x4 b1v = *(const f32x4*)(bo1 + d0);
    const int kt_o = d0>>5, lane_o = (((d0&31)>>3)<<4) + n16, j0 = d0&7;
    u32* fl = flags + (r<<3);

    for (int oct=0; oct<8; ++oct){
      if (tid == 0){
        while (__hip_atomic_load(&fl[oct], __ATOMIC_ACQUIRE, __HIP_MEMORY_SCOPE_AGENT) < 2u)
          __builtin_amdgcn_s_sleep(4);
      }
      __syncthreads();
      const int mtb = (r<<6) + (oct<<3);
      // o1 = tanh(h @ W0 + b0)
#pragma unroll
      for (int s=0;s<8;++s){
        int mt = mtb + s;
        f16x8 Bh = *(const f16x8*)(hG + ((mt*64+l)<<3));
        f32x4 acc = b0v;
        acc = MFMA16(W0a, Bh, acc);
        f16x4 z4;
#pragma unroll
        for (int i=0;i<4;++i) z4[i] = (f16)tanhfast(acc[i]);
        *(f16x4*)(&o1b[(((s*4+kt_o)*64 + lane_o)<<3) + j0]) = z4;
      }
      __syncthreads();
      // o2 = tanh(o1 @ W1 + b1)
#pragma unroll
      for (int s=0;s<8;++s){
        f32x4 acc = b1v;
#pragma unroll
        for (int kt=0;kt<4;++kt){
          f16x8 B = *(const f16x8*)(&o1b[((s*4+kt)*64 + l)<<3]);
          acc = MFMA16(W1a[kt], B, acc);
        }
        f16x4 z4;
#pragma unroll
        for (int i=0;i<4;++i) z4[i] = (f16)tanhfast(acc[i]);
        *(f16x4*)(&o2b[(((s*4+kt_o)*64 + lane_o)<<3) + j0]) = z4;
      }
      __syncthreads();
      // o3 = o2 @ W2 + b2 -> out; wave w handles subtile w
      {
        f32x4 acc = {0,0,0,0};
#pragma unroll
        for (int kt=0;kt<4;++kt){
          f16x8 B = *(const f16x8*)(&o2b[((wid*4+kt)*64 + l)<<3]);
          acc = MFMA16(W2a[kt], B, acc);
        }
        if (l < 16){
          int mt = mtb + wid, grow = (mt>>6)*16 + n16, tt = mt & 63;
#pragma unroll
          for (int i=0;i<3;++i)
            out[(grow*64 + tt)*3 + i] = acc[i] + bo2[i];
        }
      }
    }
  }
}

extern "C" void kernel_launch(void* const* d_in, const int* in_sizes, int n_in,
                              void* d_out, int out_size, void* d_ws, size_t ws_size,
                              hipStream_t stream){
  const float* x        = (const float*)d_in[0];
  const float* init_ori = (const float*)d_in[1];
  f16* wp = (f16*)d_ws;
  u32* flags = (u32*)(wp + FLAG_ELEM);

  PackSrcs ps;
  ps.p[0] = (const float*)d_in[2];   // qbA_W0
  ps.p[1] = (const float*)d_in[6];   // qbB_W0
  ps.p[2] = (const float*)d_in[4];   // qbA_Ws
  ps.p[3] = (const float*)d_in[8];   // qbB_Ws
  ps.p[4] = (const float*)d_in[10];  // alpha_W
  ps.p[5] = (const float*)d_in[12];  // beta_W
  ps.p[6] = (const float*)d_in[14];  // out_W0
  ps.p[7] = (const float*)d_in[16];  // out_W1
  ps.p[8] = (const float*)d_in[18];  // out_W2
  pack_all<<<(PACK_TOTAL+1024+255)/256, 256, 0, stream>>>(ps, wp);

  lmsc_fused<<<256,512,0,stream>>>(x, init_ori, wp,
      (const float*)d_in[3],  (const float*)d_in[5],   // qbA_b0, qbA_bs
      (const float*)d_in[7],  (const float*)d_in[9],   // qbB_b0, qbB_bs
      (const float*)d_in[11], (const float*)d_in[13],  // alpha_b, beta_b
      (const float*)d_in[15], (const float*)d_in[17], (const float*)d_in[19],
      wp + OFF_HH, flags, (float*)d_out);
}

// Round 6
// 135.609 us; speedup vs baseline: 1.2611x; 1.2611x over previous
//
#include <hip/hip_runtime.h>

typedef _Float16 f16;
typedef _Float16 f16x4 __attribute__((ext_vector_type(4)));
typedef _Float16 f16x8 __attribute__((ext_vector_type(8)));
typedef float f32x4 __attribute__((ext_vector_type(4)));
typedef unsigned int u32;

#define MFMA16(a,b,c) __builtin_amdgcn_mfma_f32_16x16x32_f16(a,b,c,0,0,0)

// raw barrier: orders LDS (lgkmcnt) but does NOT drain vmcnt (neutral vs
// __syncthreads in R3; kept so hG stores never gate a barrier).
#define BAR() asm volatile("s_waitcnt lgkmcnt(0)\n\ts_barrier" ::: "memory")

// packed weight f16-element offsets in d_ws
#define OFF_A0 0
#define OFF_B0 8192
#define OFF_AW 16384
#define OFF_BW 65536
#define OFF_AL 114688
#define OFF_BE 118784
#define OFF_O0 122880
#define OFF_O1 126976
#define OFF_O2 143360
#define PACK_TOTAL 145408
#define OFF_HH 262144                 // h plane (single f16): 8192 mt * 512

struct PackSrcs { const float* p[9]; };

// One fused pack kernel: W[K][N] fp32 -> MFMA fragment order f16.
// frag element (nt,kt,lane,j) = W[kt*32 + (lane>>4)*8 + j][nt*16 + (lane&15)]
// W0 segments: h-rows only, packed into K-tile 0 (packed row k <- source row
// 6+k, k<32); xn rows are handled by the f32 U-precompute in lmsc_rec.
__global__ __launch_bounds__(256) void pack_all(PackSrcs ps, f16* __restrict__ dst){
  int idx = blockIdx.x*256 + threadIdx.x;
  if (idx >= PACK_TOTAL) return;
  const float* src; int base, Kreal, Nreal, KT;
  if (idx < 16384){
    if (idx < 8192){ src=ps.p[0]; base=0; } else { src=ps.p[1]; base=8192; }
    Kreal=38; Nreal=128; KT=2;
  } else if (idx < 65536){
    int s=(idx-16384)>>14; src=ps.p[2]+s*16384; base=16384+s*16384; Kreal=128; Nreal=128; KT=4;
  } else if (idx < 114688){
    int s=(idx-65536)>>14; src=ps.p[3]+s*16384; base=65536+s*16384; Kreal=128; Nreal=128; KT=4;
  } else if (idx < 122880){
    if (idx<118784){ src=ps.p[4]; base=114688; } else { src=ps.p[5]; base=118784; }
    Kreal=128; Nreal=32; KT=4;
  } else if (idx < 126976){
    src=ps.p[6]; base=122880; Kreal=32; Nreal=128; KT=1;
  } else if (idx < 143360){
    src=ps.p[7]; base=126976; Kreal=128; Nreal=128; KT=4;
  } else {
    src=ps.p[8]; base=143360; Kreal=128; Nreal=3; KT=4;
  }
  int local = idx - base;
  int j = local & 7, lane = (local>>3)&63, rem = local>>9;
  int kt = rem % KT, nt = rem / KT;
  int k = kt*32 + ((lane>>4)<<3) + j;
  int n = nt*16 + (lane&15);
  if (base < 16384) k = (k < 32) ? (k + 6) : 99;   // h-rows into tile 0; tile 1 zero
  dst[idx] = (f16)((k<Kreal && n<Nreal) ? src[k*Nreal+n] : 0.f);
}

__device__ __forceinline__ float tanhfast(float x){
  float e = __builtin_amdgcn_exp2f(x * 2.885390082f);   // 2*log2(e)
  return 1.f - 2.f*__builtin_amdgcn_rcpf(e + 1.f);
}
__device__ __forceinline__ float expfast(float x){
  return __builtin_amdgcn_exp2f(x * 1.44269504f);
}

__device__ __forceinline__ f16x8 ldW(const f16* wp, int off, int KT, int nt, int kt, int l){
  return *(const f16x8*)(wp + off + (((nt*KT + kt)*64 + l)<<3));
}

// single-plane quadratic phase (transposed orientation, m=1 per wave)
template<int LAST>
__device__ __forceinline__ void qphase(const f16* __restrict__ Zi, f16* __restrict__ Zo,
                                       const f16x8 (&WA)[4], const f16x8 (&WB)[4],
                                       const float* __restrict__ bA,
                                       const float* __restrict__ bB,
                                       int l, int d0, int n16){
  f16x8 Bq[4];
#pragma unroll
  for (int kt=0; kt<4; ++kt) Bq[kt] = *(const f16x8*)(Zi + ((kt*64 + l)<<3));
  f32x4 a = *(const f32x4*)(bA + d0);
  f32x4 c = *(const f32x4*)(bB + d0);
#pragma unroll
  for (int kt=0; kt<4; ++kt){
    a = MFMA16(WA[kt], Bq[kt], a);
    c = MFMA16(WB[kt], Bq[kt], c);
  }
  f16x4 z4;
#pragma unroll
  for (int i=0;i<4;++i){
    float z = LAST ? tanhfast(a[i]*c[i]) : tanhfast(a[i])*tanhfast(c[i]);
    z4[i] = (f16)z;
  }
  int kt_o = d0>>5, lane_o = (((d0&31)>>3)<<4) | n16, j0 = d0&7;
  *(f16x4*)(Zo + ((kt_o*64 + lane_o)<<3) + j0) = z4;
}

// Recurrence: 128 blocks x 512 threads (8 waves, m=1 each, 2 waves/SIMD).
// R3 structure; L0 halved via f32 U-precompute of the xn contribution and
// single-K-tile h; P4 S-writes vectorized (2x ds_write_b64 per plane pair).
__global__ __launch_bounds__(512,2)
void lmsc_rec(const float* __restrict__ x, const float* __restrict__ init_ori,
              const f16* __restrict__ wp,
              const float* __restrict__ w0Araw, const float* __restrict__ w0Braw,
              const float* __restrict__ ba0, const float* __restrict__ bas,
              const float* __restrict__ bb0, const float* __restrict__ bbs,
              const float* __restrict__ b_al, const float* __restrict__ b_be,
              f16* __restrict__ hG)
{
  __shared__ __align__(16) f16 S[2][512];      // [hi|lo] h-plane, K=32 rows
  __shared__ __align__(16) f16 Z[2][2048];     // ping-pong, single plane, K=128
  __shared__ float biasA[4][128], biasB[4][128], biasAB[64];
  __shared__ float hbuf[512];                  // [c*16+r]
  __shared__ float xnL[64][8];                 // xn[t][0..5], sn at [6]
  __shared__ __align__(16) float UA[64][128];  // bias + W0A_xn^T @ xn_t (f32)
  __shared__ __align__(16) float UC[64][128];  // bias + W0B_xn^T @ xn_t (f32)

  const int tid = (int)threadIdx.x;
  const int l = tid & 63, wid = tid >> 6;      // 8 waves
  const int n16 = l & 15, rhi = l >> 4;
  const int d0 = (wid<<4) + (rhi<<2);          // this wave's 16-dim slice
  const int tile = (int)blockIdx.x, b = tile >> 4, Rbase = tile << 4;

  // ---- register-resident weight fragments (A-frags of W^T) ----
  f16x8 w0A = ldW(wp, OFF_A0, 2, wid, 0, l);
  f16x8 w0B = ldW(wp, OFF_B0, 2, wid, 0, l);
  f16x8 wqA[3][4], wqB[3][4];
#pragma unroll
  for (int ly=0;ly<3;++ly)
#pragma unroll
    for (int kt=0;kt<4;++kt){
      wqA[ly][kt] = ldW(wp, OFF_AW + ly*16384, 4, wid, kt, l);
      wqB[ly][kt] = ldW(wp, OFF_BW + ly*16384, 4, wid, kt, l);
    }
  f16x8 wal[4], wbe[4];
  if (wid < 2){
#pragma unroll
    for (int kt=0;kt<4;++kt){
      wal[kt] = ldW(wp, OFF_AL, 4, wid, kt, l);
      wbe[kt] = ldW(wp, OFF_BE, 4, wid, kt, l);
    }
  }

  // ---- init ----
  if (tid < 128){
    biasA[0][tid] = ba0[tid]; biasB[0][tid] = bb0[tid];
#pragma unroll
    for (int j=0;j<3;++j){ biasA[1+j][tid] = bas[j*128+tid]; biasB[1+j][tid] = bbs[j*128+tid]; }
  }
  if (tid < 32){ biasAB[tid] = b_al[tid]; biasAB[32+tid] = b_be[tid]; }
  if (tid < 64){
    const float* xp = x + (b*64 + tid)*6;
    float s2 = 0.f;
#pragma unroll
    for (int i=0;i<6;++i) s2 += xp[i]*xp[i];
    float sn = sqrtf(s2);
    float inv = 1.f/(sn + 1e-15f);
#pragma unroll
    for (int i=0;i<6;++i) xnL[tid][i] = xp[i]*inv;
    xnL[tid][6] = sn;
  }
  __syncthreads();
  // U precompute: 4 threads per dim, 16 t each; W0 xn-rows read once per thread.
  {
    const int dim = tid & 127, t0 = (tid >> 7) << 4;
    float wA[6], wC[6];
#pragma unroll
    for (int k=0;k<6;++k){ wA[k] = w0Araw[k*128+dim]; wC[k] = w0Braw[k*128+dim]; }
    const float bA_ = biasA[0][dim], bC_ = biasB[0][dim];
#pragma unroll
    for (int tt=0;tt<16;++tt){
      int t = t0 + tt;
      float aA = bA_, aC = bC_;
#pragma unroll
      for (int k=0;k<6;++k){
        float xv = xnL[t][k];
        aA += xv * wA[k];
        aC += xv * wC[k];
      }
      UA[t][dim] = aA; UC[t][dim] = aC;
    }
  }
  if (tid < 256){
    int r = tid & 15, cc = tid >> 4;
#pragma unroll
    for (int e=0;e<2;++e){
      int c = cc + e*16;
      float h0 = (c < 3) ? init_ori[(Rbase + r)*3 + c] : 0.f;
      hbuf[c*16 + r] = h0;
      f16 hh = (f16)h0, hl = (f16)(h0 - (float)hh);
      int idx = ((((c>>3)<<4) | r)<<3) + (c&7);
      S[0][idx] = hh; S[1][idx] = hl;
    }
  }
  __syncthreads();

  for (int t=0; t<64; ++t){
    // ---- L0: Z0 = tanh(U_A + W0A_h^T@h) * tanh(U_C + W0B_h^T@h) ----
    {
      f16x8 Bh = *(const f16x8*)(&S[0][l<<3]);
      f16x8 Bl = *(const f16x8*)(&S[1][l<<3]);
      f32x4 aH = *(const f32x4*)(&UA[t][d0]);
      f32x4 cH = *(const f32x4*)(&UC[t][d0]);
      f32x4 aL = {0,0,0,0}, cL = {0,0,0,0};
      aH = MFMA16(w0A, Bh, aH); aL = MFMA16(w0A, Bl, aL);
      cH = MFMA16(w0B, Bh, cH); cL = MFMA16(w0B, Bl, cL);
      f16x4 z4;
#pragma unroll
      for (int i=0;i<4;++i)
        z4[i] = (f16)(tanhfast(aH[i]+aL[i]) * tanhfast(cH[i]+cL[i]));
      int kt_o = d0>>5, lane_o = (((d0&31)>>3)<<4) | n16, j0 = d0&7;
      *(f16x4*)(&Z[0][((kt_o*64 + lane_o)<<3) + j0]) = z4;
    }
    BAR();
    qphase<0>(Z[0], Z[1], wqA[0], wqB[0], biasA[1], biasB[1], l, d0, n16);
    BAR();
    qphase<0>(Z[1], Z[0], wqA[1], wqB[1], biasA[2], biasB[2], l, d0, n16);
    BAR();
    qphase<1>(Z[0], Z[1], wqA[2], wqB[2], biasA[3], biasB[3], l, d0, n16);
    BAR();
    // ---- P4: alpha+beta+h-update on waves 0-1 (dims d0<32) ----
    if (wid < 2){
      f16x8 q[4];
#pragma unroll
      for (int kt=0;kt<4;++kt) q[kt] = *(const f16x8*)(&Z[1][(kt*64+l)<<3]);
      f32x4 ua = *(const f32x4*)(&biasAB[d0]);
      f32x4 ub = *(const f32x4*)(&biasAB[32+d0]);
#pragma unroll
      for (int kt=0;kt<4;++kt){
        ua = MFMA16(wal[kt], q[kt], ua);
        ub = MFMA16(wbe[kt], q[kt], ub);
      }
      float sn = xnL[t][6];
      int mt = tile*64 + t;
      f16x4 hh4, hl4;
#pragma unroll
      for (int i=0;i<4;++i){
        float alv = expfast(fminf(ua[i], 80.f));
        float bev = tanhfast(ub[i]);
        int c = d0 + i;
        float hold = hbuf[c*16 + n16];
        float hn = __builtin_amdgcn_exp2f(-1.44269504f*alv*sn)*(hold - bev) + bev;
        hbuf[c*16 + n16] = hn;
        f16 hh = (f16)hn; hh4[i] = hh; hl4[i] = (f16)(hn - (float)hh);
      }
      if (t < 63){
        int sb = ((((d0>>3)<<4) | n16)<<3) + (d0&7);
        *(f16x4*)(&S[0][sb]) = hh4;
        *(f16x4*)(&S[1][sb]) = hl4;
      }
      int lane_o = ((d0>>3)<<4) | n16;
      *(f16x4*)(hG + mt*512 + lane_o*8 + (d0&7)) = hh4;
    }
    BAR();
  }
}

// Deferred output head: batched GEMM over all 8192 (tile,t) M-tiles, 256 CUs.
__global__ __launch_bounds__(512,4)
void lmsc_out(const f16* __restrict__ wp, const f16* __restrict__ hG,
              const float* __restrict__ bo0, const float* __restrict__ bo1,
              const float* __restrict__ bo2, float* __restrict__ out)
{
  __shared__ __align__(16) f16 o1b[16384];   // [s][kt][lane][8]
  __shared__ __align__(16) f16 o2b[16384];
  const int tid=(int)threadIdx.x, l=tid&63, wid=tid>>6;
  const int n16=l&15, rhi=l>>4;
  const int mtb = (int)blockIdx.x * 8;
  f16x8 W0a = ldW(wp, OFF_O0, 1, wid, 0, l);
  f16x8 W1a[4], W2a[4];
#pragma unroll
  for (int kt=0;kt<4;++kt){ W1a[kt]=ldW(wp,OFF_O1,4,wid,kt,l); W2a[kt]=ldW(wp,OFF_O2,4,0,kt,l); }
  const int d0 = wid*16 + rhi*4;
  const f32x4 b0v = *(const f32x4*)(bo0 + d0);
  const f32x4 b1v = *(const f32x4*)(bo1 + d0);
  const int kt_o = d0>>5, lane_o = (((d0&31)>>3)<<4) + n16, j0 = d0&7;
  // o1 = tanh(h @ W0 + b0), single-plane h
#pragma unroll
  for (int s=0;s<8;++s){
    int mt = mtb + s;
    f16x8 Bh = *(const f16x8*)(hG + ((mt*64+l)<<3));
    f32x4 acc = b0v;
    acc = MFMA16(W0a, Bh, acc);
    f16x4 z4;
#pragma unroll
    for (int i=0;i<4;++i) z4[i] = (f16)tanhfast(acc[i]);
    *(f16x4*)(&o1b[(((s*4+kt_o)*64 + lane_o)<<3) + j0]) = z4;
  }
  __syncthreads();
  // o2 = tanh(o1 @ W1 + b1)
#pragma unroll
  for (int s=0;s<8;++s){
    f32x4 acc = b1v;
#pragma unroll
    for (int kt=0;kt<4;++kt){
      f16x8 B = *(const f16x8*)(&o1b[((s*4+kt)*64 + l)<<3]);
      acc = MFMA16(W1a[kt], B, acc);
    }
    f16x4 z4;
#pragma unroll
    for (int i=0;i<4;++i) z4[i] = (f16)tanhfast(acc[i]);
    *(f16x4*)(&o2b[(((s*4+kt_o)*64 + lane_o)<<3) + j0]) = z4;
  }
  __syncthreads();
  // o3 = o2 @ W2 + b2 -> out; wave w handles subtile w
  {
    f32x4 acc = {0,0,0,0};
#pragma unroll
    for (int kt=0;kt<4;++kt){
      f16x8 B = *(const f16x8*)(&o2b[((wid*4+kt)*64 + l)<<3]);
      acc = MFMA16(W2a[kt], B, acc);
    }
    if (l < 16){
      int mt = mtb + wid, grow = (mt>>6)*16 + n16, tt = mt & 63;
#pragma unroll
      for (int i=0;i<3;++i)
        out[(grow*64 + tt)*3 + i] = acc[i] + bo2[i];
    }
  }
}

extern "C" void kernel_launch(void* const* d_in, const int* in_sizes, int n_in,
                              void* d_out, int out_size, void* d_ws, size_t ws_size,
                              hipStream_t stream){
  const float* x        = (const float*)d_in[0];
  const float* init_ori = (const float*)d_in[1];
  f16* wp = (f16*)d_ws;

  PackSrcs ps;
  ps.p[0] = (const float*)d_in[2];   // qbA_W0
  ps.p[1] = (const float*)d_in[6];   // qbB_W0
  ps.p[2] = (const float*)d_in[4];   // qbA_Ws
  ps.p[3] = (const float*)d_in[8];   // qbB_Ws
  ps.p[4] = (const float*)d_in[10];  // alpha_W
  ps.p[5] = (const float*)d_in[12];  // beta_W
  ps.p[6] = (const float*)d_in[14];  // out_W0
  ps.p[7] = (const float*)d_in[16];  // out_W1
  ps.p[8] = (const float*)d_in[18];  // out_W2
  pack_all<<<(PACK_TOTAL+255)/256, 256, 0, stream>>>(ps, wp);

  lmsc_rec<<<128,512,0,stream>>>(x, init_ori, wp,
      (const float*)d_in[2],  (const float*)d_in[6],   // raw W0 for U-precompute
      (const float*)d_in[3],  (const float*)d_in[5],   // qbA_b0, qbA_bs
      (const float*)d_in[7],  (const float*)d_in[9],   // qbB_b0, qbB_bs
      (const float*)d_in[11], (const float*)d_in[13],  // alpha_b, beta_b
      wp + OFF_HH);
  lmsc_out<<<1024,512,0,stream>>>(wp, wp + OFF_HH,
      (const float*)d_in[15], (const float*)d_in[17], (const float*)d_in[19],
      (float*)d_out);
}